// Round 7
// baseline (40215.234 us; speedup 1.0000x reference)
//
#include <hip/hip_runtime.h>
#include <math.h>

#define B  64
#define T  256
#define S  512
#define IN 512
#define H  512
#define P  256
#define C  512

typedef _Float16 f16x8 __attribute__((ext_vector_type(8)));
typedef float    f32x4 __attribute__((ext_vector_type(4)));
typedef unsigned short u16x8 __attribute__((ext_vector_type(8)));

#define MFMA16(a, b, c) __builtin_amdgcn_mfma_f32_16x16x32_f16(a, b, c, 0, 0, 0)

// ---- ws byte offsets (shared by prep + persistent kernel) ----
#define O_C0      0
#define O_C1      131072
#define O_H0F0    262144
#define O_H0F1    393216
#define O_H1F0    524288
#define O_H1F1    655360
#define O_FEEDF   786432
#define O_BAR     851968      /* bar uses dwords [0..560]; page is zeroed */
#define O_CNT     855040      /* per-batch merge counters (64 u32), zeroed */
#define O_XF0     856064      /* zero region = [0, 856064) = 209*4096 */
#define O_XF1     987136
#define O_Q       1118208
#define O_SCORES  1249280     /* p = exp(sc-20), [B][S] */
#define O_PM      1380352     /* unused */
#define O_PS      1381376
#define O_PEA     1382400
#define O_ECTXF   1906688
#define O_BCAT0   2037760
#define O_BCAT1   2045952
#define O_W0F     2054144
#define O_W1F     12539904
#define O_WATTF   20928512
#define O_WPROJF  21977088

__device__ __forceinline__ float sigm(float x) { return 1.f / (1.f + __expf(-x)); }

__device__ __forceinline__ void split2(float v, unsigned short& hi, unsigned short& lo)
{
    _Float16 h = (_Float16)v;
    float r = (v - (float)h) * 4096.f;
    _Float16 l2 = (_Float16)r;
    union { _Float16 f; unsigned short u; } a, b2;
    a.f = h; b2.f = l2;
    hi = a.u; lo = b2.u;
}

// A-fragment layout (segment-local), validated rounds 3-6.
__device__ __forceinline__ int frag_us(int r, int k)
{
    return ((((k >> 5) * 4 + (r >> 4)) * 64 + ((k >> 3) & 3) * 16 + (r & 15)) * 16) + (k & 7);
}

// Two-level grid barrier (validated R6). Gen broadcast spread over 32 lines.
__device__ __forceinline__ void gbar(unsigned* bar, unsigned tgt, int bid, bool wrote)
{
    __syncthreads();
    if (threadIdx.x == 0) {
        if (wrote) __builtin_amdgcn_fence(__ATOMIC_RELEASE, "agent");
        const int grp = bid & 31;
        unsigned o1 = __hip_atomic_fetch_add(&bar[grp], 1u, __ATOMIC_RELAXED, __HIP_MEMORY_SCOPE_AGENT);
        if (o1 == 7u) {
            unsigned o2 = __hip_atomic_fetch_add(&bar[32], 1u, __ATOMIC_RELAXED, __HIP_MEMORY_SCOPE_AGENT);
            if (o2 == 31u) {
#pragma unroll
                for (int i = 0; i < 33; ++i)
                    __hip_atomic_store(&bar[i], 0u, __ATOMIC_RELAXED, __HIP_MEMORY_SCOPE_AGENT);
#pragma unroll
                for (int i = 0; i < 32; ++i)
                    __hip_atomic_store(&bar[64 + i * 16], tgt, __ATOMIC_RELEASE, __HIP_MEMORY_SCOPE_AGENT);
            }
        }
        while (__hip_atomic_load(&bar[64 + grp * 16], __ATOMIC_RELAXED, __HIP_MEMORY_SCOPE_AGENT) < tgt)
            __builtin_amdgcn_s_sleep(1);
        __builtin_amdgcn_fence(__ATOMIC_ACQUIRE, "agent");
    }
    __syncthreads();
}

// fp16x2 3-term MFMA GEMM core (validated): 16 output cols (tile ct), 64 rows,
// K = nks*32 split 8-way across waves; partials to red[] in LDS.
__device__ __forceinline__ void gemm_core(
    const unsigned short* A0, int n0, const unsigned short* A1, int n1,
    const unsigned short* A2, const unsigned short* Wf, int nks, int ct,
    float* red, int tid)
{
    const int l = tid & 63, kh = tid >> 6;          // kh 0..7
    f32x4 acch[4] = {};
    f32x4 accl[4] = {};
    const int KQ = nks >> 3;
#pragma unroll 2
    for (int i = 0; i < KQ; ++i) {
        const int ks = kh * KQ + i;
        const unsigned short* ap; int ksl;
        if (ks < n0)           { ap = A0; ksl = ks; }
        else if (ks < n0 + n1) { ap = A1; ksl = ks - n0; }
        else                   { ap = A2; ksl = ks - n0 - n1; }
        const f16x8* bp = (const f16x8*)(Wf + ((long)(ct * nks + ks) * 64 + l) * 16);
        const f16x8 bh = bp[0];
        const f16x8 bl = bp[1];
#pragma unroll
        for (int mt = 0; mt < 4; ++mt) {
            const f16x8* app = (const f16x8*)(ap + (((ksl * 4 + mt) * 64 + l) * 16));
            const f16x8 ah = app[0];
            const f16x8 al = app[1];
            acch[mt] = MFMA16(ah, bh, acch[mt]);
            accl[mt] = MFMA16(ah, bl, accl[mt]);
            accl[mt] = MFMA16(al, bh, accl[mt]);
        }
    }
#pragma unroll
    for (int mt = 0; mt < 4; ++mt) {
        f32x4 v = acch[mt] + accl[mt] * (1.f / 4096.f);
        *(f32x4*)&red[(kh * 64 + l) * 20 + mt * 4] = v;
    }
}

// LSTM pointwise epilogue over 8 K-partials (call with tid < 256).
__device__ __forceinline__ void lstm_epi(const float* red, const float* bias,
                                         float* cbuf, unsigned short* hfrag,
                                         int ct, int tid)
{
    const int b = tid & 63, hl = tid >> 6;
    float g4[4];
#pragma unroll
    for (int g = 0; g < 4; ++g) {
        const int col = hl * 4 + g;
        const int li  = ((b & 15) >> 2) * 16 + col;
        const int ri  = (b >> 4) * 4 + (b & 3);
        float v = bias[ct * 16 + col];
#pragma unroll
        for (int k2 = 0; k2 < 8; ++k2) v += red[(k2 * 64 + li) * 20 + ri];
        g4[g] = v;
    }
    const int hg = ct * 4 + hl;
    const float cold = cbuf[b * H + hg];
    const float cn = sigm(g4[1]) * cold + sigm(g4[0]) * tanhf(g4[2]);
    cbuf[b * H + hg] = cn;
    const float hn = sigm(g4[3]) * tanhf(cn);
    unsigned short hi, lo; split2(hn, hi, lo);
    const int fu = frag_us(b, hg);
    hfrag[fu]     = hi;
    hfrag[fu + 8] = lo;
}

// ---------------------------------------------------------------------------
// The whole T-loop in one cooperative kernel. Grid MUST be 256 x 512.
// ---------------------------------------------------------------------------
__global__ __launch_bounds__(512)
void decoder_persistent(const float* __restrict__ dec_input,
                        const float* __restrict__ ctx,
                        const float* __restrict__ mask,
                        const float* __restrict__ bproj,
                        char* __restrict__ wsb,
                        float* __restrict__ out)
{
    __shared__ float lds[10240];   // 40 KB: GEMM reduce (8*64*20) / attn scratch

    float*          c0     = (float*)(wsb + O_C0);
    float*          c1     = (float*)(wsb + O_C1);
    unsigned short* h0f[2] = {(unsigned short*)(wsb + O_H0F0), (unsigned short*)(wsb + O_H0F1)};
    unsigned short* h1f[2] = {(unsigned short*)(wsb + O_H1F0), (unsigned short*)(wsb + O_H1F1)};
    unsigned short* feedf  = (unsigned short*)(wsb + O_FEEDF);
    unsigned*       bar    = (unsigned*)(wsb + O_BAR);
    unsigned*       cnt    = (unsigned*)(wsb + O_CNT);
    unsigned short* xf[2]  = {(unsigned short*)(wsb + O_XF0), (unsigned short*)(wsb + O_XF1)};
    float*          qbuf   = (float*)(wsb + O_Q);
    float*          pS     = (float*)(wsb + O_SCORES);
    float*          Ps     = (float*)(wsb + O_PS);
    float*          Pea    = (float*)(wsb + O_PEA);
    unsigned short* ectxf  = (unsigned short*)(wsb + O_ECTXF);
    const float*    bcat0  = (const float*)(wsb + O_BCAT0);
    const float*    bcat1  = (const float*)(wsb + O_BCAT1);
    const unsigned short* W0f    = (const unsigned short*)(wsb + O_W0F);
    const unsigned short* W1f    = (const unsigned short*)(wsb + O_W1F);
    const unsigned short* Wattf  = (const unsigned short*)(wsb + O_WATTF);
    const unsigned short* Wprojf = (const unsigned short*)(wsb + O_WPROJF);

    float* dec_out = out;
    float* att_out = out + (long)B * T * P;

    const int bid = blockIdx.x;
    const int tid = threadIdx.x;
    unsigned tgt = 0;

    for (int t = 0; t < T; ++t) {
        // ---- K1: LSTM layer 0 (blocks 0-127); x_{t+1} convert (128-191) ----
        if (bid < 128) {
            gemm_core(xf[t & 1], 16, feedf, 8, h0f[t & 1], W0f, 40, bid, lds, tid);
            __syncthreads();
            if (tid < 256) lstm_epi(lds, bcat0, c0, h0f[(t + 1) & 1], bid, tid);
        } else if (bid < 192 && t + 1 < T) {
            const int idx = (bid - 128) * 512 + tid;    // 0..32767
            const int bb = idx >> 9, k = idx & 511;
            unsigned short hi, lo;
            split2(dec_input[((long)bb * T + (t + 1)) * IN + k], hi, lo);
            unsigned short* dst = xf[(t + 1) & 1];
            const int fu = frag_us(bb, k);
            dst[fu]     = hi;
            dst[fu + 8] = lo;
        }
        gbar(bar, ++tgt, bid, bid < 192);

        // ---- K2: LSTM layer 1 ----
        if (bid < 128) {
            gemm_core(h0f[(t + 1) & 1], 16, h1f[t & 1], 16, nullptr, W1f, 32, bid, lds, tid);
            __syncthreads();
            if (tid < 256) lstm_epi(lds, bcat1, c1, h1f[(t + 1) & 1], bid, tid);
        }
        gbar(bar, ++tgt, bid, bid < 128);

        // ---- Q: q = h1 @ Watt ----
        if (bid < 32) {
            gemm_core(h1f[(t + 1) & 1], 16, nullptr, 0, nullptr, Wattf, 16, bid, lds, tid);
            __syncthreads();
            if (tid < 256) {
                const int b = tid & 63, cl = tid >> 6;
                float4 vv;
#pragma unroll
                for (int c2 = 0; c2 < 4; ++c2) {
                    const int col = cl * 4 + c2;
                    const int li  = ((b & 15) >> 2) * 16 + col;
                    const int ri  = (b >> 4) * 4 + (b & 3);
                    float v = 0.f;
#pragma unroll
                    for (int k2 = 0; k2 < 8; ++k2) v += lds[(k2 * 64 + li) * 20 + ri];
                    ((float*)&vv)[c2] = v;
                }
                *(float4*)(qbuf + b * C + bid * 16 + cl * 4) = vv;
            }
        }
        gbar(bar, ++tgt, bid, bid < 32);

        // ---- ATTN (+fused per-b MERGE): block=(b,quarter), 8 tiles x 16 rows.
        //      Tile staged in LDS via register prefetch (4 indep dwordx4/thr
        //      always in flight); q held in registers; both passes read LDS.
        //      Fixed softmax shift m=20 (scores bounded; exact semantics). ----
        {
            const int b = bid >> 2, qd = bid & 3;
            float*    tile  = lds;                 // 16 x 516 floats (padded)
            float*    scl   = lds + 8300;          // 128 p-values
            unsigned* mflag = (unsigned*)(lds + 8448);

            const int ch  = tid & 31;              // 32 c-chunks (4 c x 4 groups)
            const int rl2 = tid >> 5;              // row 0..15 in tile

            float4 qv[4];
#pragma unroll
            for (int j4 = 0; j4 < 4; ++j4)
                qv[j4] = *(const float4*)(qbuf + (long)b * C + ch * 4 + j4 * 128);

            const float* cbase = ctx + ((long)b * S + qd * 128) * C;
            float4 creg[4];
#pragma unroll
            for (int it = 0; it < 4; ++it) {
                const int i = tid + it * 512;
                const int r = i >> 7, c4 = i & 127;
                creg[it] = *(const float4*)(cbase + (long)r * C + c4 * 4);
            }

            float eacc = 0.f;

            for (int tt = 0; tt < 8; ++tt) {
                // write staged registers to LDS tile
#pragma unroll
                for (int it = 0; it < 4; ++it) {
                    const int i = tid + it * 512;
                    const int r = i >> 7, c4 = i & 127;
                    *(float4*)&tile[r * 516 + c4 * 4] = creg[it];
                }
                __syncthreads();
                // prefetch next tile into registers (overlaps both passes)
                if (tt + 1 < 8) {
#pragma unroll
                    for (int it = 0; it < 4; ++it) {
                        const int i = tid + it * 512;
                        const int r = i >> 7, c4 = i & 127;
                        creg[it] = *(const float4*)(cbase + (long)((tt + 1) * 16 + r) * C + c4 * 4);
                    }
                }
                // pass 1: score for row rl2 (lane-contiguous float4 LDS reads)
                float part = 0.f;
#pragma unroll
                for (int j4 = 0; j4 < 4; ++j4) {
                    const float4 cv = *(const float4*)&tile[rl2 * 516 + (ch + j4 * 32) * 4];
                    part = fmaf(cv.x, qv[j4].x, part);
                    part = fmaf(cv.y, qv[j4].y, part);
                    part = fmaf(cv.z, qv[j4].z, part);
                    part = fmaf(cv.w, qv[j4].w, part);
                }
                part += __shfl_xor(part, 1);
                part += __shfl_xor(part, 2);
                part += __shfl_xor(part, 4);
                part += __shfl_xor(part, 8);
                part += __shfl_xor(part, 16);
                if (ch == 0) {
                    const int srow = qd * 128 + tt * 16 + rl2;
                    const float sc = part + (mask[(long)b * S + srow] - 1.f) * 1e9f;
                    const float p  = __expf(sc - 20.f);
                    scl[tt * 16 + rl2] = p;
                    pS[(long)b * S + srow] = p;
                }
                __syncthreads();
                // pass 2: ectx partial, c = tid (conflict-free scalar reads)
#pragma unroll
                for (int s = 0; s < 16; ++s)
                    eacc = fmaf(scl[tt * 16 + s], tile[s * 516 + tid], eacc);
                __syncthreads();               // before next tile overwrite
            }

            Pea[(long)bid * 512 + tid] = eacc;
            if (tid < 64) {
                float v = scl[tid] + scl[tid + 64];
#pragma unroll
                for (int off = 32; off; off >>= 1) v += __shfl_xor(v, off);
                if (tid == 0) Ps[bid] = v;
            }
            __syncthreads();                   // drain all writes (vmcnt 0)
            if (tid == 0) {
                __builtin_amdgcn_fence(__ATOMIC_RELEASE, "agent");
                unsigned r = __hip_atomic_fetch_add(&cnt[b], 1u, __ATOMIC_RELAXED, __HIP_MEMORY_SCOPE_AGENT);
                const unsigned last = (unsigned)(t * 4 + 3);
                *mflag = (r == last) ? 1u : 0u;
                if (r == last) __builtin_amdgcn_fence(__ATOMIC_ACQUIRE, "agent");
            }
            __syncthreads();
            if (*mflag) {                      // last quarter merges batch b
                const float gs = Ps[b * 4] + Ps[b * 4 + 1] + Ps[b * 4 + 2] + Ps[b * 4 + 3];
                const float inv = 1.f / gs;
                float v = Pea[(long)(b * 4 + 0) * 512 + tid] + Pea[(long)(b * 4 + 1) * 512 + tid]
                        + Pea[(long)(b * 4 + 2) * 512 + tid] + Pea[(long)(b * 4 + 3) * 512 + tid];
                v *= inv;
                unsigned short hi, lo; split2(v, hi, lo);
                const int fu = frag_us(b, tid);
                ectxf[fu]     = hi;
                ectxf[fu + 8] = lo;
                att_out[((long)b * T + t) * S + tid] = pS[(long)b * S + tid] * inv;
            }
        }
        gbar(bar, ++tgt, bid, true);

        // ---- PROJ: tanh([h1|ectx] @ Wproj^T + b) -> dec_out + feed frags ----
        if (bid < 16) {
            gemm_core(h1f[(t + 1) & 1], 16, ectxf, 16, nullptr, Wprojf, 32, bid, lds, tid);
            __syncthreads();
            if (tid < 256) {
                const int b = tid & 63, cl = tid >> 6;
                float4 vv;
#pragma unroll
                for (int c2 = 0; c2 < 4; ++c2) {
                    const int col = cl * 4 + c2;
                    const int li  = ((b & 15) >> 2) * 16 + col;
                    const int ri  = (b >> 4) * 4 + (b & 3);
                    float v = bproj[bid * 16 + col];
#pragma unroll
                    for (int k2 = 0; k2 < 8; ++k2) v += lds[(k2 * 64 + li) * 20 + ri];
                    v = tanhf(v);
                    ((float*)&vv)[c2] = v;
                    unsigned short hi, lo; split2(v, hi, lo);
                    const int fu = frag_us(b, bid * 16 + col);
                    feedf[fu]     = hi;
                    feedf[fu + 8] = lo;
                }
                *(float4*)(dec_out + ((long)b * T + t) * P + bid * 16 + cl * 4) = vv;
            }
        }
        gbar(bar, ++tgt, bid, bid < 16);
    }
}

// ---------------------------------------------------------------------------
// One-time prep (validated rounds 4-6): zero state+barriers+counters, x0
// fragments, combined biases, and all weight fragment buffers.
// ---------------------------------------------------------------------------
__global__ __launch_bounds__(256)
void prep_all(const float* __restrict__ dec_input,
              const float* __restrict__ Wih0, const float* __restrict__ Whh0,
              const float* __restrict__ bih0, const float* __restrict__ bhh0,
              const float* __restrict__ Wih1, const float* __restrict__ Whh1,
              const float* __restrict__ bih1, const float* __restrict__ bhh1,
              const float* __restrict__ Watt, const float* __restrict__ Wproj,
              char* __restrict__ wsb)
{
    const int bid = blockIdx.x, tid = threadIdx.x;
    if (bid < 209) {                                   // zero [0, 856064)
        float4 z = {0.f, 0.f, 0.f, 0.f};
        ((float4*)wsb)[bid * 256 + tid] = z;
    } else if (bid < 337) {                            // x0 fragments
        const int idx = (bid - 209) * 256 + tid;       // 0..32767
        const int bb = idx >> 9, k = idx & 511;
        unsigned short hi, lo;
        split2(dec_input[((long)bb * T) * IN + k], hi, lo);
        unsigned short* xf0 = (unsigned short*)(wsb + O_XF0);
        const int fu = frag_us(bb, k);
        xf0[fu] = hi; xf0[fu + 8] = lo;
    } else if (bid < 353) {                            // combined biases
        const int idx = (bid - 337) * 256 + tid;       // 0..4095
        if (idx < 2048) {
            const int p = idx, h = p >> 2, g = p & 3, orig = g * H + h;
            ((float*)(wsb + O_BCAT0))[p] = bih0[orig] + bhh0[orig];
        } else {
            const int p = idx - 2048, h = p >> 2, g = p & 3, orig = g * H + h;
            ((float*)(wsb + O_BCAT1))[p] = bih1[orig] + bhh1[orig];
        }
    } else if (bid < 481) {                            // Wattf (n=c 512, k=h 512, NKS=16)
        const int idx = (bid - 353) * 256 + tid;       // 0..32767
        const int n = idx >> 6, k = (idx & 63) * 8;
        u16x8 hv, lv;
#pragma unroll
        for (int j = 0; j < 8; ++j) {
            unsigned short hi, lo; split2(Watt[(long)(k + j) * C + n], hi, lo);
            hv[j] = hi; lv[j] = lo;
        }
        unsigned short* Wf = (unsigned short*)(wsb + O_WATTF);
        const long base = ((long)((n >> 4) * 16 + (k >> 5)) * 64 + ((k >> 3) & 3) * 16 + (n & 15)) * 16;
        *(u16x8*)(Wf + base)     = hv;
        *(u16x8*)(Wf + base + 8) = lv;
    } else if (bid < 609) {                            // Wprojf (n=p 256, k 1024, NKS=32)
        const int idx = (bid - 481) * 256 + tid;       // 0..32767
        const int n = idx >> 7, k = (idx & 127) * 8;
        const float* src = Wproj + (long)n * (H + C) + k;
        u16x8 hv, lv;
#pragma unroll
        for (int j = 0; j < 8; ++j) {
            unsigned short hi, lo; split2(src[j], hi, lo);
            hv[j] = hi; lv[j] = lo;
        }
        unsigned short* Wf = (unsigned short*)(wsb + O_WPROJF);
        const long base = ((long)((n >> 4) * 32 + (k >> 5)) * 64 + ((k >> 3) & 3) * 16 + (n & 15)) * 16;
        *(u16x8*)(Wf + base)     = hv;
        *(u16x8*)(Wf + base + 8) = lv;
    } else if (bid < 1889) {                           // W0f (NKS=40, gate-interleaved)
        const int idx = (bid - 609) * 256 + tid;       // 0..327679
        const int n = idx / 160, k8 = idx - n * 160;
        const int k = k8 * 8;
        const int h = n >> 2, g = n & 3, orig = g * H + h;
        const float* src = (k < IN + P) ? (Wih0 + (long)orig * (IN + P) + k)
                                        : (Whh0 + (long)orig * H + (k - (IN + P)));
        u16x8 hv, lv;
#pragma unroll
        for (int j = 0; j < 8; ++j) {
            unsigned short hi, lo; split2(src[j], hi, lo);
            hv[j] = hi; lv[j] = lo;
        }
        unsigned short* Wf = (unsigned short*)(wsb + O_W0F);
        const long base = ((long)((n >> 4) * 40 + (k >> 5)) * 64 + ((k >> 3) & 3) * 16 + (n & 15)) * 16;
        *(u16x8*)(Wf + base)     = hv;
        *(u16x8*)(Wf + base + 8) = lv;
    } else {                                           // W1f (NKS=32), blocks 1889..2913
        const int idx = (bid - 1889) * 256 + tid;      // 0..262143
        const int n = idx >> 7, k = (idx & 127) * 8;
        const int h = n >> 2, g = n & 3, orig = g * H + h;
        const float* src = (k < H) ? (Wih1 + (long)orig * H + k)
                                   : (Whh1 + (long)orig * H + (k - H));
        u16x8 hv, lv;
#pragma unroll
        for (int j = 0; j < 8; ++j) {
            unsigned short hi, lo; split2(src[j], hi, lo);
            hv[j] = hi; lv[j] = lo;
        }
        unsigned short* Wf = (unsigned short*)(wsb + O_W1F);
        const long base = ((long)((n >> 4) * 32 + (k >> 5)) * 64 + ((k >> 3) & 3) * 16 + (n & 15)) * 16;
        *(u16x8*)(Wf + base)     = hv;
        *(u16x8*)(Wf + base + 8) = lv;
    }
}

extern "C" void kernel_launch(void* const* d_in, const int* in_sizes, int n_in,
                              void* d_out, int out_size, void* d_ws, size_t ws_size,
                              hipStream_t stream)
{
    (void)in_sizes; (void)n_in; (void)out_size; (void)ws_size;
    const float* dec_input = (const float*)d_in[0];
    const float* ctx       = (const float*)d_in[1];
    const float* mask      = (const float*)d_in[2];
    const float* Wih0      = (const float*)d_in[3];
    const float* Whh0      = (const float*)d_in[4];
    const float* bih0      = (const float*)d_in[5];
    const float* bhh0      = (const float*)d_in[6];
    const float* Wih1      = (const float*)d_in[7];
    const float* Whh1      = (const float*)d_in[8];
    const float* bih1      = (const float*)d_in[9];
    const float* bhh1      = (const float*)d_in[10];
    const float* Watt      = (const float*)d_in[11];
    const float* Wproj     = (const float*)d_in[12];
    const float* bproj     = (const float*)d_in[13];
    float* out = (float*)d_out;
    char*  wsb = (char*)d_ws;

    prep_all<<<2913, 256, 0, stream>>>(dec_input, Wih0, Whh0, bih0, bhh0,
                                       Wih1, Whh1, bih1, bhh1, Watt, Wproj, wsb);

    void* args[] = {(void*)&dec_input, (void*)&ctx, (void*)&mask, (void*)&bproj,
                    (void*)&wsb, (void*)&out};
    hipLaunchCooperativeKernel((const void*)decoder_persistent,
                               dim3(256), dim3(512), args, 0, stream);
}

// Round 8
// 19468.147 us; speedup vs baseline: 2.0657x; 2.0657x over previous
//
#include <hip/hip_runtime.h>
#include <math.h>

#define B  64
#define T  256
#define S  512
#define IN 512
#define H  512
#define P  256
#define C  512

typedef _Float16 f16x8 __attribute__((ext_vector_type(8)));
typedef float    f32x4 __attribute__((ext_vector_type(4)));
typedef unsigned short u16x8 __attribute__((ext_vector_type(8)));

#define MFMA16(a, b, c) __builtin_amdgcn_mfma_f32_16x16x32_f16(a, b, c, 0, 0, 0)

// ---- ws byte offsets ----
#define O_C0      0           /* 131072 */
#define O_C1      131072      /* 131072 */
#define O_H0F0    262144      /* 131072 */
#define O_H0F1    393216
#define O_H1F0    524288
#define O_H1F1    655360
#define O_FEEDF   786432      /* 65536 */
#define O_H1F32   851968      /* 131072 ; zero region = [0, 983040) = 240*4096 */
#define O_XF0     983040      /* 131072 */
#define O_XF1     1114112     /* 131072 */
#define O_Q       1245184     /* 131072 */
#define O_PS      1376256     /* 2048: Ps[512] */
#define O_PSP     1378304     /* 131072: pS[64][512] */
#define O_PEA     1509376     /* 1048576: Pea[512][512] */
#define O_BCAT0   2557952     /* 8192 */
#define O_BCAT1   2566144     /* 8192 */
#define O_WPROJT  2574336     /* 1048576: fp32 [1024][256] */
#define O_W0F     3622912     /* 10485760 */
#define O_W1F     14108672    /* 8388608 */
#define O_WATTF   22497280    /* 1048576 */
/* end 23545856 */

__device__ __forceinline__ float sigm(float x) { return 1.f / (1.f + __expf(-x)); }

__device__ __forceinline__ void split2(float v, unsigned short& hi, unsigned short& lo)
{
    _Float16 h = (_Float16)v;
    float r = (v - (float)h) * 4096.f;
    _Float16 l2 = (_Float16)r;
    union { _Float16 f; unsigned short u; } a, b2;
    a.f = h; b2.f = l2;
    hi = a.u; lo = b2.u;
}

// A-fragment layout (segment-local), validated rounds 3-7.
__device__ __forceinline__ int frag_us(int r, int k)
{
    return ((((k >> 5) * 4 + (r >> 4)) * 64 + ((k >> 3) & 3) * 16 + (r & 15)) * 16) + (k & 7);
}

// fp16x2 3-term MFMA GEMM core (validated R5-R7): 16 output cols (tile ct),
// 64 rows, K = nks*32 split 8-way across waves; partials to red[] in LDS.
__device__ __forceinline__ void gemm_core(
    const unsigned short* A0, int n0, const unsigned short* A1, int n1,
    const unsigned short* A2, const unsigned short* Wf, int nks, int ct,
    float* red, int tid)
{
    const int l = tid & 63, kh = tid >> 6;          // kh 0..7
    f32x4 acch[4] = {};
    f32x4 accl[4] = {};
    const int KQ = nks >> 3;
#pragma unroll 2
    for (int i = 0; i < KQ; ++i) {
        const int ks = kh * KQ + i;
        const unsigned short* ap; int ksl;
        if (ks < n0)           { ap = A0; ksl = ks; }
        else if (ks < n0 + n1) { ap = A1; ksl = ks - n0; }
        else                   { ap = A2; ksl = ks - n0 - n1; }
        const f16x8* bp = (const f16x8*)(Wf + ((long)(ct * nks + ks) * 64 + l) * 16);
        const f16x8 bh = bp[0];
        const f16x8 bl = bp[1];
#pragma unroll
        for (int mt = 0; mt < 4; ++mt) {
            const f16x8* app = (const f16x8*)(ap + (((ksl * 4 + mt) * 64 + l) * 16));
            const f16x8 ah = app[0];
            const f16x8 al = app[1];
            acch[mt] = MFMA16(ah, bh, acch[mt]);
            accl[mt] = MFMA16(ah, bl, accl[mt]);
            accl[mt] = MFMA16(al, bh, accl[mt]);
        }
    }
#pragma unroll
    for (int mt = 0; mt < 4; ++mt) {
        f32x4 v = acch[mt] + accl[mt] * (1.f / 4096.f);
        *(f32x4*)&red[(kh * 64 + l) * 20 + mt * 4] = v;
    }
}

// LSTM pointwise epilogue over 8 K-partials (call with tid < 256).
__device__ __forceinline__ void lstm_epi(const float* red, const float* bias,
                                         float* cbuf, unsigned short* hfrag,
                                         float* hf32, int ct, int tid)
{
    const int b = tid & 63, hl = tid >> 6;
    float g4[4];
#pragma unroll
    for (int g = 0; g < 4; ++g) {
        const int col = hl * 4 + g;
        const int li  = ((b & 15) >> 2) * 16 + col;
        const int ri  = (b >> 4) * 4 + (b & 3);
        float v = bias[ct * 16 + col];
#pragma unroll
        for (int k2 = 0; k2 < 8; ++k2) v += red[(k2 * 64 + li) * 20 + ri];
        g4[g] = v;
    }
    const int hg = ct * 4 + hl;
    const float cold = cbuf[b * H + hg];
    const float cn = sigm(g4[1]) * cold + sigm(g4[0]) * tanhf(g4[2]);
    cbuf[b * H + hg] = cn;
    const float hn = sigm(g4[3]) * tanhf(cn);
    unsigned short hi, lo; split2(hn, hi, lo);
    const int fu = frag_us(b, hg);
    hfrag[fu]     = hi;
    hfrag[fu + 8] = lo;
    if (hf32) hf32[b * H + hg] = hn;
}

// ---------------------------------------------------------------------------
// K1: LSTM layer 0 (blocks 0-127) + x_{t+1} fragment convert (128-191)
// ---------------------------------------------------------------------------
__global__ __launch_bounds__(512)
void k1_kernel(char* __restrict__ wsb, const float* __restrict__ dec_input, int t)
{
    __shared__ float lds[10240];
    const int bid = blockIdx.x, tid = threadIdx.x;
    unsigned short* h0f[2] = {(unsigned short*)(wsb + O_H0F0), (unsigned short*)(wsb + O_H0F1)};
    unsigned short* xf[2]  = {(unsigned short*)(wsb + O_XF0), (unsigned short*)(wsb + O_XF1)};

    if (bid < 128) {
        gemm_core(xf[t & 1], 16, (unsigned short*)(wsb + O_FEEDF), 8, h0f[t & 1],
                  (const unsigned short*)(wsb + O_W0F), 40, bid, lds, tid);
        __syncthreads();
        if (tid < 256)
            lstm_epi(lds, (const float*)(wsb + O_BCAT0), (float*)(wsb + O_C0),
                     h0f[(t + 1) & 1], nullptr, bid, tid);
    } else if (t + 1 < T) {
        const int idx = (bid - 128) * 512 + tid;    // 0..32767
        const int bb = idx >> 9, k = idx & 511;
        unsigned short hi, lo;
        split2(dec_input[((long)bb * T + (t + 1)) * IN + k], hi, lo);
        unsigned short* dst = xf[(t + 1) & 1];
        const int fu = frag_us(bb, k);
        dst[fu]     = hi;
        dst[fu + 8] = lo;
    }
}

// ---------------------------------------------------------------------------
// K2: LSTM layer 1 (128 blocks); also writes h1 in fp32 for merge/proj.
// ---------------------------------------------------------------------------
__global__ __launch_bounds__(512)
void k2_kernel(char* __restrict__ wsb, int t)
{
    __shared__ float lds[10240];
    const int bid = blockIdx.x, tid = threadIdx.x;
    unsigned short* h0f[2] = {(unsigned short*)(wsb + O_H0F0), (unsigned short*)(wsb + O_H0F1)};
    unsigned short* h1f[2] = {(unsigned short*)(wsb + O_H1F0), (unsigned short*)(wsb + O_H1F1)};

    gemm_core(h0f[(t + 1) & 1], 16, h1f[t & 1], 16, nullptr,
              (const unsigned short*)(wsb + O_W1F), 32, bid, lds, tid);
    __syncthreads();
    if (tid < 256)
        lstm_epi(lds, (const float*)(wsb + O_BCAT1), (float*)(wsb + O_C1),
                 h1f[(t + 1) & 1], (float*)(wsb + O_H1F32), bid, tid);
}

// ---------------------------------------------------------------------------
// Q: q = h1 @ Watt via MFMA fragments (32 blocks), fp32 out.
// ---------------------------------------------------------------------------
__global__ __launch_bounds__(512)
void q_kernel(char* __restrict__ wsb, int t)
{
    __shared__ float lds[10240];
    const int bid = blockIdx.x, tid = threadIdx.x;
    unsigned short* h1f[2] = {(unsigned short*)(wsb + O_H1F0), (unsigned short*)(wsb + O_H1F1)};
    float* qbuf = (float*)(wsb + O_Q);

    gemm_core(h1f[(t + 1) & 1], 16, nullptr, 0, nullptr,
              (const unsigned short*)(wsb + O_WATTF), 16, bid, lds, tid);
    __syncthreads();
    if (tid < 256) {
        const int b = tid & 63, cl = tid >> 6;
        float4 vv;
#pragma unroll
        for (int c2 = 0; c2 < 4; ++c2) {
            const int col = cl * 4 + c2;
            const int li  = ((b & 15) >> 2) * 16 + col;
            const int ri  = (b >> 4) * 4 + (b & 3);
            float v = 0.f;
#pragma unroll
            for (int k2 = 0; k2 < 8; ++k2) v += lds[(k2 * 64 + li) * 20 + ri];
            ((float*)&vv)[c2] = v;
        }
        *(float4*)(qbuf + b * C + bid * 16 + cl * 4) = vv;
    }
}

// ---------------------------------------------------------------------------
// QATTN: 512 blocks = (b, eighth of S). Each block streams its 64-row ctx
// slice ONCE via 32-row LDS tiles with 8 independent dwordx4/thread register
// prefetch. Fixed softmax shift m=20 (scores bounded; exact semantics).
// Writes Pea[bid][512] (unnormalized ectx partial), Ps[bid], pS[b][s].
// ---------------------------------------------------------------------------
__global__ __launch_bounds__(512)
void qattn_kernel(char* __restrict__ wsb, const float* __restrict__ ctx,
                  const float* __restrict__ mask, int t)
{
    __shared__ float qs[512];
    __shared__ float tile[32 * 516];
    __shared__ float scl[64];

    const int bid = blockIdx.x, tid = threadIdx.x;
    const int b = bid >> 3, ei = bid & 7;          // rows [ei*64, ei*64+64)
    const float* qbuf = (const float*)(wsb + O_Q);
    float* pS  = (float*)(wsb + O_PSP);
    float* Ps  = (float*)(wsb + O_PS);
    float* Pea = (float*)(wsb + O_PEA);

    if (tid < 128) ((float4*)qs)[tid] = ((const float4*)(qbuf + (long)b * C))[tid];
    __syncthreads();

    const int row = tid >> 4;                      // 0..31 within tile
    const int ch  = tid & 15;                      // 32-c chunk
    float4 qv[8];
#pragma unroll
    for (int j4 = 0; j4 < 8; ++j4)
        qv[j4] = *(const float4*)&qs[ch * 32 + j4 * 4];

    const float* cbase = ctx + ((long)b * S + ei * 64) * C;
    float4 creg[8];
#pragma unroll
    for (int it = 0; it < 8; ++it) {
        const int i = it * 512 + tid;
        const int r = i >> 7, c4 = i & 127;
        creg[it] = *(const float4*)(cbase + (long)r * C + c4 * 4);
    }

    float eacc = 0.f;
#pragma unroll
    for (int tt = 0; tt < 2; ++tt) {
        // write staged registers to LDS tile
#pragma unroll
        for (int it = 0; it < 8; ++it) {
            const int i = it * 512 + tid;
            const int r = (i >> 7) & 31, c4 = i & 127;
            *(float4*)&tile[r * 516 + c4 * 4] = creg[it];
        }
        __syncthreads();
        // prefetch next 32-row tile
        if (tt == 0) {
#pragma unroll
            for (int it = 0; it < 8; ++it) {
                const int i = it * 512 + tid;
                const int r = i >> 7, c4 = i & 127;
                creg[it] = *(const float4*)(cbase + (long)(32 + r) * C + c4 * 4);
            }
        }
        // pass 1: scores (16 threads/row, lane-contiguous float4 LDS reads)
        float part = 0.f;
#pragma unroll
        for (int j4 = 0; j4 < 8; ++j4) {
            const float4 cv = *(const float4*)&tile[row * 516 + ch * 32 + j4 * 4];
            part = fmaf(cv.x, qv[j4].x, part);
            part = fmaf(cv.y, qv[j4].y, part);
            part = fmaf(cv.z, qv[j4].z, part);
            part = fmaf(cv.w, qv[j4].w, part);
        }
        part += __shfl_xor(part, 1);
        part += __shfl_xor(part, 2);
        part += __shfl_xor(part, 4);
        part += __shfl_xor(part, 8);
        if (ch == 0) {
            const int srow = ei * 64 + tt * 32 + row;
            const float sc = part + (mask[(long)b * S + srow] - 1.f) * 1e9f;
            const float p  = __expf(sc - 20.f);
            scl[tt * 32 + row] = p;
            pS[(long)b * S + srow] = p;
        }
        __syncthreads();
        // pass 2: ectx partial, c = tid (consecutive-lane LDS reads, 2-way ok)
#pragma unroll 8
        for (int s = 0; s < 32; ++s)
            eacc = fmaf(scl[tt * 32 + s], tile[s * 516 + tid], eacc);
        __syncthreads();
    }

    Pea[(long)bid * 512 + tid] = eacc;
    if (tid < 64) {
        float v = scl[tid];
#pragma unroll
        for (int off = 32; off; off >>= 1) v += __shfl_xor(v, off);
        if (tid == 0) Ps[bid] = v;
    }
}

// ---------------------------------------------------------------------------
// MERGEPROJ: 64 blocks (one per batch). Merge 8 eighth-partials -> ectx,
// write alpha, then VALU projection tanh([h1|ectx]@Wproj^T+b) -> dec_out +
// feed fragments. Fence-free (kernel boundary provides sync).
// ---------------------------------------------------------------------------
__global__ __launch_bounds__(512)
void mergeproj_kernel(char* __restrict__ wsb, const float* __restrict__ bproj,
                      float* __restrict__ out, int t)
{
    __shared__ float ectx[512];
    __shared__ float h1l[512];
    __shared__ float red[512];

    const int b = blockIdx.x, tid = threadIdx.x;
    const float* Ps  = (const float*)(wsb + O_PS);
    const float* Pea = (const float*)(wsb + O_PEA);
    const float* pS  = (const float*)(wsb + O_PSP);
    const float* h1f32 = (const float*)(wsb + O_H1F32);
    const float* WprojT = (const float*)(wsb + O_WPROJT);
    unsigned short* feedf = (unsigned short*)(wsb + O_FEEDF);

    float* dec_out = out;
    float* att_out = out + (long)B * T * P;

    float gs = 0.f;
#pragma unroll
    for (int j = 0; j < 8; ++j) gs += Ps[b * 8 + j];
    const float inv = 1.f / gs;

    float v = 0.f;
#pragma unroll
    for (int j = 0; j < 8; ++j) v += Pea[(long)(b * 8 + j) * 512 + tid];
    ectx[tid] = v * inv;
    h1l[tid]  = h1f32[(long)b * H + tid];
    att_out[((long)b * T + t) * S + tid] = pS[(long)b * S + tid] * inv;
    __syncthreads();

    const int p = tid & 255, half = tid >> 8;
    const float* al = half ? ectx : h1l;
    const float* Wp = WprojT + (long)(half * 512) * P + p;
    float acc = 0.f;
#pragma unroll 8
    for (int kk = 0; kk < 512; ++kk)
        acc = fmaf(al[kk], Wp[(long)kk * P], acc);
    red[tid] = acc;
    __syncthreads();

    if (tid < 256) {
        float vv = red[tid] + red[tid + 256] + bproj[tid];
        vv = tanhf(vv);
        dec_out[((long)b * T + t) * P + tid] = vv;
        unsigned short hi, lo; split2(vv, hi, lo);
        const int fu = frag_us(b, tid);
        feedf[fu]     = hi;
        feedf[fu + 8] = lo;
    }
}

// ---------------------------------------------------------------------------
// One-time prep: zero state, x0 fragments, combined biases, Wattf fragments,
// WprojT fp32, W0f/W1f fragments (gate-interleaved). Grid 3840 x 256.
// ---------------------------------------------------------------------------
__global__ __launch_bounds__(256)
void prep_all(const float* __restrict__ dec_input,
              const float* __restrict__ Wih0, const float* __restrict__ Whh0,
              const float* __restrict__ bih0, const float* __restrict__ bhh0,
              const float* __restrict__ Wih1, const float* __restrict__ Whh1,
              const float* __restrict__ bih1, const float* __restrict__ bhh1,
              const float* __restrict__ Watt, const float* __restrict__ Wproj,
              char* __restrict__ wsb)
{
    const int bid = blockIdx.x, tid = threadIdx.x;
    if (bid < 240) {                                   // zero [0, 983040)
        float4 z = {0.f, 0.f, 0.f, 0.f};
        ((float4*)wsb)[bid * 256 + tid] = z;
    } else if (bid < 368) {                            // x0 fragments
        const int idx = (bid - 240) * 256 + tid;       // 0..32767
        const int bb = idx >> 9, k = idx & 511;
        unsigned short hi, lo;
        split2(dec_input[((long)bb * T) * IN + k], hi, lo);
        unsigned short* xf0 = (unsigned short*)(wsb + O_XF0);
        const int fu = frag_us(bb, k);
        xf0[fu] = hi; xf0[fu + 8] = lo;
    } else if (bid < 384) {                            // combined biases
        const int idx = (bid - 368) * 256 + tid;       // 0..4095
        if (idx < 2048) {
            const int p = idx, h = p >> 2, g = p & 3, orig = g * H + h;
            ((float*)(wsb + O_BCAT0))[p] = bih0[orig] + bhh0[orig];
        } else {
            const int p = idx - 2048, h = p >> 2, g = p & 3, orig = g * H + h;
            ((float*)(wsb + O_BCAT1))[p] = bih1[orig] + bhh1[orig];
        }
    } else if (bid < 512) {                            // Wattf (n=c, k=h, NKS=16)
        const int idx = (bid - 384) * 256 + tid;       // 0..32767
        const int n = idx >> 6, k = (idx & 63) * 8;
        u16x8 hv, lv;
#pragma unroll
        for (int j = 0; j < 8; ++j) {
            unsigned short hi, lo; split2(Watt[(long)(k + j) * C + n], hi, lo);
            hv[j] = hi; lv[j] = lo;
        }
        unsigned short* Wf = (unsigned short*)(wsb + O_WATTF);
        const long base = ((long)((n >> 4) * 16 + (k >> 5)) * 64 + ((k >> 3) & 3) * 16 + (n & 15)) * 16;
        *(u16x8*)(Wf + base)     = hv;
        *(u16x8*)(Wf + base + 8) = lv;
    } else if (bid < 1536) {                           // WprojT fp32 [1024][256]
        const int idx = (bid - 512) * 256 + tid;       // 0..262143
        const int k = idx >> 8, p = idx & 255;
        ((float*)(wsb + O_WPROJT))[k * P + p] = Wproj[(long)p * (H + C) + k];
    } else if (bid < 2816) {                           // W0f (NKS=40)
        const int idx = (bid - 1536) * 256 + tid;      // 0..327679
        const int n = idx / 160, k8 = idx - n * 160;
        const int k = k8 * 8;
        const int h = n >> 2, g = n & 3, orig = g * H + h;
        const float* src = (k < IN + P) ? (Wih0 + (long)orig * (IN + P) + k)
                                        : (Whh0 + (long)orig * H + (k - (IN + P)));
        u16x8 hv, lv;
#pragma unroll
        for (int j = 0; j < 8; ++j) {
            unsigned short hi, lo; split2(src[j], hi, lo);
            hv[j] = hi; lv[j] = lo;
        }
        unsigned short* Wf = (unsigned short*)(wsb + O_W0F);
        const long base = ((long)((n >> 4) * 40 + (k >> 5)) * 64 + ((k >> 3) & 3) * 16 + (n & 15)) * 16;
        *(u16x8*)(Wf + base)     = hv;
        *(u16x8*)(Wf + base + 8) = lv;
    } else {                                           // W1f (NKS=32): 2816..3839
        const int idx = (bid - 2816) * 256 + tid;      // 0..262143
        const int n = idx >> 7, k = (idx & 127) * 8;
        const int h = n >> 2, g = n & 3, orig = g * H + h;
        const float* src = (k < H) ? (Wih1 + (long)orig * H + k)
                                   : (Whh1 + (long)orig * H + (k - H));
        u16x8 hv, lv;
#pragma unroll
        for (int j = 0; j < 8; ++j) {
            unsigned short hi, lo; split2(src[j], hi, lo);
            hv[j] = hi; lv[j] = lo;
        }
        unsigned short* Wf = (unsigned short*)(wsb + O_W1F);
        const long base = ((long)((n >> 4) * 32 + (k >> 5)) * 64 + ((k >> 3) & 3) * 16 + (n & 15)) * 16;
        *(u16x8*)(Wf + base)     = hv;
        *(u16x8*)(Wf + base + 8) = lv;
    }
}

extern "C" void kernel_launch(void* const* d_in, const int* in_sizes, int n_in,
                              void* d_out, int out_size, void* d_ws, size_t ws_size,
                              hipStream_t stream)
{
    (void)in_sizes; (void)n_in; (void)out_size; (void)ws_size;
    const float* dec_input = (const float*)d_in[0];
    const float* ctx       = (const float*)d_in[1];
    const float* mask      = (const float*)d_in[2];
    const float* Wih0      = (const float*)d_in[3];
    const float* Whh0      = (const float*)d_in[4];
    const float* bih0      = (const float*)d_in[5];
    const float* bhh0      = (const float*)d_in[6];
    const float* Wih1      = (const float*)d_in[7];
    const float* Whh1      = (const float*)d_in[8];
    const float* bih1      = (const float*)d_in[9];
    const float* bhh1      = (const float*)d_in[10];
    const float* Watt      = (const float*)d_in[11];
    const float* Wproj     = (const float*)d_in[12];
    const float* bproj     = (const float*)d_in[13];
    float* out = (float*)d_out;
    char*  wsb = (char*)d_ws;

    prep_all<<<3840, 256, 0, stream>>>(dec_input, Wih0, Whh0, bih0, bhh0,
                                       Wih1, Whh1, bih1, bhh1, Watt, Wproj, wsb);

    for (int t = 0; t < T; ++t) {
        k1_kernel<<<192, 512, 0, stream>>>(wsb, dec_input, t);
        k2_kernel<<<128, 512, 0, stream>>>(wsb, t);
        q_kernel<<<32, 512, 0, stream>>>(wsb, t);
        qattn_kernel<<<512, 512, 0, stream>>>(wsb, ctx, mask, t);
        mergeproj_kernel<<<64, 512, 0, stream>>>(wsb, bproj, out, t);
    }
}

// Round 9
// 14791.806 us; speedup vs baseline: 2.7188x; 1.3161x over previous
//
#include <hip/hip_runtime.h>
#include <math.h>

#define B  64
#define T  256
#define S  512
#define IN 512
#define H  512
#define P  256
#define C  512

typedef _Float16 f16x8 __attribute__((ext_vector_type(8)));
typedef float    f32x4 __attribute__((ext_vector_type(4)));
typedef unsigned short u16x8 __attribute__((ext_vector_type(8)));

#define MFMA16(a, b, c) __builtin_amdgcn_mfma_f32_16x16x32_f16(a, b, c, 0, 0, 0)

// ---- ws byte offsets ----
#define O_C0      0           /* 131072 */
#define O_C1      131072      /* 131072 */
#define O_H0F0    262144      /* 131072 */
#define O_H0F1    393216
#define O_H1F0    524288
#define O_H1F1    655360
#define O_FEEDF   786432      /* 65536 */
#define O_H1F32   851968      /* 131072 ; zero region = [0, 983040) = 240*4096 */
#define O_XF0     983040      /* 131072 */
#define O_XF1     1114112     /* 131072 */
#define O_Q       1245184     /* 131072 */
#define O_PS      1376256     /* 2048: Ps[512] */
#define O_PSP     1378304     /* 131072: pS[64][512] */
#define O_PEA     1509376     /* 1048576: Pea[512][512] */
#define O_BCAT0   2557952     /* 8192 */
#define O_BCAT1   2566144     /* 8192 */
#define O_WPROJT  2574336     /* 1048576: fp32 [1024][256] */
#define O_W0F     3622912     /* 10485760 */
#define O_W1F     14108672    /* 8388608 */
#define O_WATTF   22497280    /* 1048576 */
#define O_CTXH    23545856    /* 33554432: fp16 ctx [B][S][C] */
/* end 57100288 */

__device__ __forceinline__ float sigm(float x) { return 1.f / (1.f + __expf(-x)); }

__device__ __forceinline__ void split2(float v, unsigned short& hi, unsigned short& lo)
{
    _Float16 h = (_Float16)v;
    float r = (v - (float)h) * 4096.f;
    _Float16 l2 = (_Float16)r;
    union { _Float16 f; unsigned short u; } a, b2;
    a.f = h; b2.f = l2;
    hi = a.u; lo = b2.u;
}

__device__ __forceinline__ unsigned short f2h(float v)
{
    union { _Float16 f; unsigned short u; } x;
    x.f = (_Float16)v;
    return x.u;
}

__device__ __forceinline__ float h2f(unsigned short u)
{
    union { unsigned short u; _Float16 f; } x;
    x.u = u;
    return (float)x.f;
}

// A-fragment layout (segment-local), validated rounds 3-8.
__device__ __forceinline__ int frag_us(int r, int k)
{
    return ((((k >> 5) * 4 + (r >> 4)) * 64 + ((k >> 3) & 3) * 16 + (r & 15)) * 16) + (k & 7);
}

// fp16x2 3-term MFMA GEMM core (validated R5-R8): 16 output cols (tile ct),
// 64 rows, K = nks*32 split 8-way across waves; partials to red[] in LDS.
__device__ __forceinline__ void gemm_core(
    const unsigned short* A0, int n0, const unsigned short* A1, int n1,
    const unsigned short* A2, const unsigned short* Wf, int nks, int ct,
    float* red, int tid)
{
    const int l = tid & 63, kh = tid >> 6;          // kh 0..7
    f32x4 acch[4] = {};
    f32x4 accl[4] = {};
    const int KQ = nks >> 3;
#pragma unroll 2
    for (int i = 0; i < KQ; ++i) {
        const int ks = kh * KQ + i;
        const unsigned short* ap; int ksl;
        if (ks < n0)           { ap = A0; ksl = ks; }
        else if (ks < n0 + n1) { ap = A1; ksl = ks - n0; }
        else                   { ap = A2; ksl = ks - n0 - n1; }
        const f16x8* bp = (const f16x8*)(Wf + ((long)(ct * nks + ks) * 64 + l) * 16);
        const f16x8 bh = bp[0];
        const f16x8 bl = bp[1];
#pragma unroll
        for (int mt = 0; mt < 4; ++mt) {
            const f16x8* app = (const f16x8*)(ap + (((ksl * 4 + mt) * 64 + l) * 16));
            const f16x8 ah = app[0];
            const f16x8 al = app[1];
            acch[mt] = MFMA16(ah, bh, acch[mt]);
            accl[mt] = MFMA16(ah, bl, accl[mt]);
            accl[mt] = MFMA16(al, bh, accl[mt]);
        }
    }
#pragma unroll
    for (int mt = 0; mt < 4; ++mt) {
        f32x4 v = acch[mt] + accl[mt] * (1.f / 4096.f);
        *(f32x4*)&red[(kh * 64 + l) * 20 + mt * 4] = v;
    }
}

// LSTM pointwise epilogue over 8 K-partials (call with tid < 256).
__device__ __forceinline__ void lstm_epi(const float* red, const float* bias,
                                         float* cbuf, unsigned short* hfrag,
                                         float* hf32, int ct, int tid)
{
    const int b = tid & 63, hl = tid >> 6;
    float g4[4];
#pragma unroll
    for (int g = 0; g < 4; ++g) {
        const int col = hl * 4 + g;
        const int li  = ((b & 15) >> 2) * 16 + col;
        const int ri  = (b >> 4) * 4 + (b & 3);
        float v = bias[ct * 16 + col];
#pragma unroll
        for (int k2 = 0; k2 < 8; ++k2) v += red[(k2 * 64 + li) * 20 + ri];
        g4[g] = v;
    }
    const int hg = ct * 4 + hl;
    const float cold = cbuf[b * H + hg];
    const float cn = sigm(g4[1]) * cold + sigm(g4[0]) * tanhf(g4[2]);
    cbuf[b * H + hg] = cn;
    const float hn = sigm(g4[3]) * tanhf(cn);
    unsigned short hi, lo; split2(hn, hi, lo);
    const int fu = frag_us(b, hg);
    hfrag[fu]     = hi;
    hfrag[fu + 8] = lo;
    if (hf32) hf32[b * H + hg] = hn;
}

// ---------------------------------------------------------------------------
// K1: LSTM layer 0 (blocks 0-127) + x_{t+1} fragment convert (128-191)
// ---------------------------------------------------------------------------
__global__ __launch_bounds__(512)
void k1_kernel(char* __restrict__ wsb, const float* __restrict__ dec_input, int t)
{
    __shared__ float lds[10240];
    const int bid = blockIdx.x, tid = threadIdx.x;
    unsigned short* h0f[2] = {(unsigned short*)(wsb + O_H0F0), (unsigned short*)(wsb + O_H0F1)};
    unsigned short* xf[2]  = {(unsigned short*)(wsb + O_XF0), (unsigned short*)(wsb + O_XF1)};

    if (bid < 128) {
        gemm_core(xf[t & 1], 16, (unsigned short*)(wsb + O_FEEDF), 8, h0f[t & 1],
                  (const unsigned short*)(wsb + O_W0F), 40, bid, lds, tid);
        __syncthreads();
        if (tid < 256)
            lstm_epi(lds, (const float*)(wsb + O_BCAT0), (float*)(wsb + O_C0),
                     h0f[(t + 1) & 1], nullptr, bid, tid);
    } else if (t + 1 < T) {
        const int idx = (bid - 128) * 512 + tid;    // 0..32767
        const int bb = idx >> 9, k = idx & 511;
        unsigned short hi, lo;
        split2(dec_input[((long)bb * T + (t + 1)) * IN + k], hi, lo);
        unsigned short* dst = xf[(t + 1) & 1];
        const int fu = frag_us(bb, k);
        dst[fu]     = hi;
        dst[fu + 8] = lo;
    }
}

// ---------------------------------------------------------------------------
// K2: LSTM layer 1 (128 blocks); also writes h1 in fp32 for merge/proj.
// ---------------------------------------------------------------------------
__global__ __launch_bounds__(512)
void k2_kernel(char* __restrict__ wsb, int t)
{
    __shared__ float lds[10240];
    const int bid = blockIdx.x, tid = threadIdx.x;
    unsigned short* h0f[2] = {(unsigned short*)(wsb + O_H0F0), (unsigned short*)(wsb + O_H0F1)};
    unsigned short* h1f[2] = {(unsigned short*)(wsb + O_H1F0), (unsigned short*)(wsb + O_H1F1)};

    gemm_core(h0f[(t + 1) & 1], 16, h1f[t & 1], 16, nullptr,
              (const unsigned short*)(wsb + O_W1F), 32, bid, lds, tid);
    __syncthreads();
    if (tid < 256)
        lstm_epi(lds, (const float*)(wsb + O_BCAT1), (float*)(wsb + O_C1),
                 h1f[(t + 1) & 1], (float*)(wsb + O_H1F32), bid, tid);
}

// ---------------------------------------------------------------------------
// Q: q = h1 @ Watt via MFMA fragments (32 blocks), fp32 out.
// ---------------------------------------------------------------------------
__global__ __launch_bounds__(512)
void q_kernel(char* __restrict__ wsb, int t)
{
    __shared__ float lds[10240];
    const int bid = blockIdx.x, tid = threadIdx.x;
    unsigned short* h1f[2] = {(unsigned short*)(wsb + O_H1F0), (unsigned short*)(wsb + O_H1F1)};
    float* qbuf = (float*)(wsb + O_Q);

    gemm_core(h1f[(t + 1) & 1], 16, nullptr, 0, nullptr,
              (const unsigned short*)(wsb + O_WATTF), 16, bid, lds, tid);
    __syncthreads();
    if (tid < 256) {
        const int b = tid & 63, cl = tid >> 6;
        float4 vv;
#pragma unroll
        for (int c2 = 0; c2 < 4; ++c2) {
            const int col = cl * 4 + c2;
            const int li  = ((b & 15) >> 2) * 16 + col;
            const int ri  = (b >> 4) * 4 + (b & 3);
            float v = 0.f;
#pragma unroll
            for (int k2 = 0; k2 < 8; ++k2) v += lds[(k2 * 64 + li) * 20 + ri];
            ((float*)&vv)[c2] = v;
        }
        *(float4*)(qbuf + b * C + bid * 16 + cl * 4) = vv;
    }
}

// ---------------------------------------------------------------------------
// QATTN: 512 blocks = (b, eighth of S). Each block streams its 64-row ctx
// slice ONCE (fp16, half the bytes of R8) via 32-row LDS tiles with register
// prefetch. Fixed softmax shift m=20 (scores bounded; exact semantics).
// Writes Pea[bid][512] (unnormalized ectx partial), Ps[bid], pS[b][s].
// ---------------------------------------------------------------------------
__global__ __launch_bounds__(512)
void qattn_kernel(char* __restrict__ wsb, const float* __restrict__ mask, int t)
{
    __shared__ float qs[512];
    __shared__ unsigned short tile[32 * 520];
    __shared__ float scl[64];

    const int bid = blockIdx.x, tid = threadIdx.x;
    const int b = bid >> 3, ei = bid & 7;          // rows [ei*64, ei*64+64)
    const float* qbuf = (const float*)(wsb + O_Q);
    const unsigned short* ctxh = (const unsigned short*)(wsb + O_CTXH);
    float* pS  = (float*)(wsb + O_PSP);
    float* Ps  = (float*)(wsb + O_PS);
    float* Pea = (float*)(wsb + O_PEA);

    if (tid < 128) ((float4*)qs)[tid] = ((const float4*)(qbuf + (long)b * C))[tid];
    __syncthreads();

    const int row = tid >> 4;                      // 0..31 within tile
    const int ch  = tid & 15;                      // 32-c chunk
    float qv[32];
#pragma unroll
    for (int j = 0; j < 32; ++j) qv[j] = qs[ch * 32 + j];

    const unsigned short* cb16 = ctxh + ((long)b * S + ei * 64) * C;
    u16x8 creg[4];
#pragma unroll
    for (int it = 0; it < 4; ++it) {
        const int i = it * 512 + tid;              // 0..2047; elem off = i*8
        creg[it] = *(const u16x8*)(cb16 + (long)i * 8);
    }

    float eacc = 0.f;
#pragma unroll
    for (int tt = 0; tt < 2; ++tt) {
        // write staged registers to LDS tile (r = i>>6, c8 = i&63)
#pragma unroll
        for (int it = 0; it < 4; ++it) {
            const int i = it * 512 + tid;
            const int r = i >> 6, c8 = i & 63;
            *(u16x8*)&tile[r * 520 + c8 * 8] = creg[it];
        }
        __syncthreads();
        // prefetch next 32-row tile
        if (tt == 0) {
#pragma unroll
            for (int it = 0; it < 4; ++it) {
                const int i = it * 512 + tid;
                creg[it] = *(const u16x8*)(cb16 + 32 * 512 + (long)i * 8);
            }
        }
        // pass 1: scores (16 threads/row, fp16 LDS reads + VALU cvt)
        float part = 0.f;
#pragma unroll
        for (int j4 = 0; j4 < 4; ++j4) {
            const u16x8 cv = *(const u16x8*)&tile[row * 520 + ch * 32 + j4 * 8];
#pragma unroll
            for (int m = 0; m < 8; ++m)
                part = fmaf(h2f(cv[m]), qv[j4 * 8 + m], part);
        }
        part += __shfl_xor(part, 1);
        part += __shfl_xor(part, 2);
        part += __shfl_xor(part, 4);
        part += __shfl_xor(part, 8);
        if (ch == 0) {
            const int srow = ei * 64 + tt * 32 + row;
            const float sc = part + (mask[(long)b * S + srow] - 1.f) * 1e9f;
            const float p  = __expf(sc - 20.f);
            scl[tt * 32 + row] = p;
            pS[(long)b * S + srow] = p;
        }
        __syncthreads();
        // pass 2: ectx partial, c = tid (consecutive-lane fp16 reads)
#pragma unroll 8
        for (int s = 0; s < 32; ++s)
            eacc = fmaf(scl[tt * 32 + s], h2f(tile[s * 520 + tid]), eacc);
        __syncthreads();
    }

    Pea[(long)bid * 512 + tid] = eacc;
    if (tid < 64) {
        float v = scl[tid];
#pragma unroll
        for (int off = 32; off; off >>= 1) v += __shfl_xor(v, off);
        if (tid == 0) Ps[bid] = v;
    }
}

// ---------------------------------------------------------------------------
// MERGEPROJ: 64 blocks (one per batch). Merge 8 eighth-partials -> ectx,
// write alpha, then VALU projection tanh([h1|ectx]@Wproj^T+b) -> dec_out +
// feed fragments. Fence-free (kernel boundary provides sync).
// ---------------------------------------------------------------------------
__global__ __launch_bounds__(512)
void mergeproj_kernel(char* __restrict__ wsb, const float* __restrict__ bproj,
                      float* __restrict__ out, int t)
{
    __shared__ float ectx[512];
    __shared__ float h1l[512];
    __shared__ float red[512];

    const int b = blockIdx.x, tid = threadIdx.x;
    const float* Ps  = (const float*)(wsb + O_PS);
    const float* Pea = (const float*)(wsb + O_PEA);
    const float* pS  = (const float*)(wsb + O_PSP);
    const float* h1f32 = (const float*)(wsb + O_H1F32);
    const float* WprojT = (const float*)(wsb + O_WPROJT);
    unsigned short* feedf = (unsigned short*)(wsb + O_FEEDF);

    float* dec_out = out;
    float* att_out = out + (long)B * T * P;

    float gs = 0.f;
#pragma unroll
    for (int j = 0; j < 8; ++j) gs += Ps[b * 8 + j];
    const float inv = 1.f / gs;

    float v = 0.f;
#pragma unroll
    for (int j = 0; j < 8; ++j) v += Pea[(long)(b * 8 + j) * 512 + tid];
    ectx[tid] = v * inv;
    h1l[tid]  = h1f32[(long)b * H + tid];
    att_out[((long)b * T + t) * S + tid] = pS[(long)b * S + tid] * inv;
    __syncthreads();

    const int p = tid & 255, half = tid >> 8;
    const float* al = half ? ectx : h1l;
    const float* Wp = WprojT + (long)(half * 512) * P + p;
    float acc = 0.f;
#pragma unroll 8
    for (int kk = 0; kk < 512; ++kk)
        acc = fmaf(al[kk], Wp[(long)kk * P], acc);
    red[tid] = acc;
    __syncthreads();

    if (tid < 256) {
        float vv = red[tid] + red[tid + 256] + bproj[tid];
        vv = tanhf(vv);
        dec_out[((long)b * T + t) * P + tid] = vv;
        unsigned short hi, lo; split2(vv, hi, lo);
        const int fu = frag_us(b, tid);
        feedf[fu]     = hi;
        feedf[fu + 8] = lo;
    }
}

// ---------------------------------------------------------------------------
// One-time prep: zero state, x0 fragments, combined biases, Wattf fragments,
// WprojT fp32, W0f/W1f fragments (gate-interleaved), ctx fp16.
// Grid 7936 x 256.
// ---------------------------------------------------------------------------
__global__ __launch_bounds__(256)
void prep_all(const float* __restrict__ dec_input,
              const float* __restrict__ Wih0, const float* __restrict__ Whh0,
              const float* __restrict__ bih0, const float* __restrict__ bhh0,
              const float* __restrict__ Wih1, const float* __restrict__ Whh1,
              const float* __restrict__ bih1, const float* __restrict__ bhh1,
              const float* __restrict__ Watt, const float* __restrict__ Wproj,
              const float* __restrict__ ctx,
              char* __restrict__ wsb)
{
    const int bid = blockIdx.x, tid = threadIdx.x;
    if (bid < 240) {                                   // zero [0, 983040)
        float4 z = {0.f, 0.f, 0.f, 0.f};
        ((float4*)wsb)[bid * 256 + tid] = z;
    } else if (bid < 368) {                            // x0 fragments
        const int idx = (bid - 240) * 256 + tid;       // 0..32767
        const int bb = idx >> 9, k = idx & 511;
        unsigned short hi, lo;
        split2(dec_input[((long)bb * T) * IN + k], hi, lo);
        unsigned short* xf0 = (unsigned short*)(wsb + O_XF0);
        const int fu = frag_us(bb, k);
        xf0[fu] = hi; xf0[fu + 8] = lo;
    } else if (bid < 384) {                            // combined biases
        const int idx = (bid - 368) * 256 + tid;       // 0..4095
        if (idx < 2048) {
            const int p = idx, h = p >> 2, g = p & 3, orig = g * H + h;
            ((float*)(wsb + O_BCAT0))[p] = bih0[orig] + bhh0[orig];
        } else {
            const int p = idx - 2048, h = p >> 2, g = p & 3, orig = g * H + h;
            ((float*)(wsb + O_BCAT1))[p] = bih1[orig] + bhh1[orig];
        }
    } else if (bid < 512) {                            // Wattf (n=c, k=h, NKS=16)
        const int idx = (bid - 384) * 256 + tid;       // 0..32767
        const int n = idx >> 6, k = (idx & 63) * 8;
        u16x8 hv, lv;
#pragma unroll
        for (int j = 0; j < 8; ++j) {
            unsigned short hi, lo; split2(Watt[(long)(k + j) * C + n], hi, lo);
            hv[j] = hi; lv[j] = lo;
        }
        unsigned short* Wf = (unsigned short*)(wsb + O_WATTF);
        const long base = ((long)((n >> 4) * 16 + (k >> 5)) * 64 + ((k >> 3) & 3) * 16 + (n & 15)) * 16;
        *(u16x8*)(Wf + base)     = hv;
        *(u16x8*)(Wf + base + 8) = lv;
    } else if (bid < 1536) {                           // WprojT fp32 [1024][256]
        const int idx = (bid - 512) * 256 + tid;       // 0..262143
        const int k = idx >> 8, p = idx & 255;
        ((float*)(wsb + O_WPROJT))[k * P + p] = Wproj[(long)p * (H + C) + k];
    } else if (bid < 2816) {                           // W0f (NKS=40)
        const int idx = (bid - 1536) * 256 + tid;      // 0..327679
        const int n = idx / 160, k8 = idx - n * 160;
        const int k = k8 * 8;
        const int h = n >> 2, g = n & 3, orig = g * H + h;
        const float* src = (k < IN + P) ? (Wih0 + (long)orig * (IN + P) + k)
                                        : (Whh0 + (long)orig * H + (k - (IN + P)));
        u16x8 hv, lv;
#pragma unroll
        for (int j = 0; j < 8; ++j) {
            unsigned short hi, lo; split2(src[j], hi, lo);
            hv[j] = hi; lv[j] = lo;
        }
        unsigned short* Wf = (unsigned short*)(wsb + O_W0F);
        const long base = ((long)((n >> 4) * 40 + (k >> 5)) * 64 + ((k >> 3) & 3) * 16 + (n & 15)) * 16;
        *(u16x8*)(Wf + base)     = hv;
        *(u16x8*)(Wf + base + 8) = lv;
    } else if (bid < 3840) {                           // W1f (NKS=32)
        const int idx = (bid - 2816) * 256 + tid;      // 0..262143
        const int n = idx >> 7, k = (idx & 127) * 8;
        const int h = n >> 2, g = n & 3, orig = g * H + h;
        const float* src = (k < H) ? (Wih1 + (long)orig * H + k)
                                   : (Whh1 + (long)orig * H + (k - H));
        u16x8 hv, lv;
#pragma unroll
        for (int j = 0; j < 8; ++j) {
            unsigned short hi, lo; split2(src[j], hi, lo);
            hv[j] = hi; lv[j] = lo;
        }
        unsigned short* Wf = (unsigned short*)(wsb + O_W1F);
        const long base = ((long)((n >> 4) * 32 + (k >> 5)) * 64 + ((k >> 3) & 3) * 16 + (n & 15)) * 16;
        *(u16x8*)(Wf + base)     = hv;
        *(u16x8*)(Wf + base + 8) = lv;
    } else {                                           // ctx -> fp16, 4096 blocks
        const long idx = (long)(bid - 3840) * 256 + tid;   // 0..1048575
        const float* src = ctx + idx * 16;
        unsigned short* dst = (unsigned short*)(wsb + O_CTXH) + idx * 16;
        u16x8 o0, o1;
#pragma unroll
        for (int j = 0; j < 8; ++j) {
            o0[j] = f2h(src[j]);
            o1[j] = f2h(src[j + 8]);
        }
        *(u16x8*)dst       = o0;
        *(u16x8*)(dst + 8) = o1;
    }
}

extern "C" void kernel_launch(void* const* d_in, const int* in_sizes, int n_in,
                              void* d_out, int out_size, void* d_ws, size_t ws_size,
                              hipStream_t stream)
{
    (void)in_sizes; (void)n_in; (void)out_size; (void)ws_size;
    const float* dec_input = (const float*)d_in[0];
    const float* ctx       = (const float*)d_in[1];
    const float* mask      = (const float*)d_in[2];
    const float* Wih0      = (const float*)d_in[3];
    const float* Whh0      = (const float*)d_in[4];
    const float* bih0      = (const float*)d_in[5];
    const float* bhh0      = (const float*)d_in[6];
    const float* Wih1      = (const float*)d_in[7];
    const float* Whh1      = (const float*)d_in[8];
    const float* bih1      = (const float*)d_in[9];
    const float* bhh1      = (const float*)d_in[10];
    const float* Watt      = (const float*)d_in[11];
    const float* Wproj     = (const float*)d_in[12];
    const float* bproj     = (const float*)d_in[13];
    float* out = (float*)d_out;
    char*  wsb = (char*)d_ws;

    prep_all<<<7936, 256, 0, stream>>>(dec_input, Wih0, Whh0, bih0, bhh0,
                                       Wih1, Whh1, bih1, bhh1, Watt, Wproj,
                                       ctx, wsb);

    for (int t = 0; t < T; ++t) {
        k1_kernel<<<192, 512, 0, stream>>>(wsb, dec_input, t);
        k2_kernel<<<128, 512, 0, stream>>>(wsb, t);
        q_kernel<<<32, 512, 0, stream>>>(wsb, t);
        qattn_kernel<<<512, 512, 0, stream>>>(wsb, mask, t);
        mergeproj_kernel<<<64, 512, 0, stream>>>(wsb, bproj, out, t);
    }
}